// Round 7
// baseline (1820.030 us; speedup 1.0000x reference)
//
#include <hip/hip_runtime.h>
#include <hip/hip_bf16.h>

// Problem constants
#define BB 64
#define TT 2048
#define II 128
#define HH 256
#define OO 128

typedef float f32x4v __attribute__((ext_vector_type(4)));
typedef short bf16x8 __attribute__((ext_vector_type(8)));
typedef unsigned short ushortv4 __attribute__((ext_vector_type(4)));

__device__ __forceinline__ float bf16bits_to_f32(unsigned short u) {
    return __uint_as_float((unsigned)u << 16);
}
__device__ __forceinline__ unsigned short f2bf(float f) {
    union { __hip_bfloat16 h; unsigned short u; } cv;
    cv.h = __float2bfloat16(f);   // RNE
    return cv.u;
}
__device__ __forceinline__ float tanh_fast(float x) {
    float e = __expf(2.0f * x);
    return 1.0f - 2.0f * __builtin_amdgcn_rcpf(e + 1.0f);
}
// within-64 permutation: storage position p holds true column true_k(p)
// true_k(p) = (p & ~63) + 16*(p&3) + ((p&63)>>2);  inverse pos(c) = (c&~63)+4*(c&15)+((c&63)>>4)
__device__ __forceinline__ int true_k(int p) {
    return (p & ~63) + 16 * (p & 3) + ((p & 63) >> 2);
}

// ---------------------------------------------------------------------------
// Phase 1 GEMM: xproj[m][pos] = (x*Wi^T)[m][true(pos)] + bi + bh  (permuted
// column layout, combined bias). Scalar scatter stores.
// ---------------------------------------------------------------------------
#define BM 64
#define BN 64
#define BKT 32

__global__ __launch_bounds__(256) void gemm_f32_bt(
    const float* __restrict__ A, const float* __restrict__ B,
    const float* __restrict__ bias, const float* __restrict__ bias2,
    float* __restrict__ C, int M, int N, int K)
{
    __shared__ __align__(16) float As[BKT][BM + 4];
    __shared__ __align__(16) float Bs[BKT][BN + 4];

    const int t  = threadIdx.x;
    const int m0 = blockIdx.x * BM;
    const int n0 = blockIdx.y * BN;
    const int r  = t >> 3;         // 0..31
    const int kq = (t & 7) * 4;    // 0,4,...,28
    const int tx = t & 15;
    const int ty = t >> 4;

    float acc[4][4] = {};

    for (int k0 = 0; k0 < K; k0 += BKT) {
        float4 a0 = *(const float4*)&A[(size_t)(m0 + r)      * K + k0 + kq];
        float4 a1 = *(const float4*)&A[(size_t)(m0 + r + 32) * K + k0 + kq];
        float4 b0 = *(const float4*)&B[(size_t)(n0 + r)      * K + k0 + kq];
        float4 b1 = *(const float4*)&B[(size_t)(n0 + r + 32) * K + k0 + kq];

        __syncthreads();
        As[kq + 0][r] = a0.x; As[kq + 1][r] = a0.y; As[kq + 2][r] = a0.z; As[kq + 3][r] = a0.w;
        As[kq + 0][r + 32] = a1.x; As[kq + 1][r + 32] = a1.y; As[kq + 2][r + 32] = a1.z; As[kq + 3][r + 32] = a1.w;
        Bs[kq + 0][r] = b0.x; Bs[kq + 1][r] = b0.y; Bs[kq + 2][r] = b0.z; Bs[kq + 3][r] = b0.w;
        Bs[kq + 0][r + 32] = b1.x; Bs[kq + 1][r + 32] = b1.y; Bs[kq + 2][r + 32] = b1.z; Bs[kq + 3][r + 32] = b1.w;
        __syncthreads();

#pragma unroll
        for (int k = 0; k < BKT; ++k) {
            float4 avv = *(const float4*)&As[k][ty * 4];
            float4 bvv = *(const float4*)&Bs[k][tx * 4];
            const float* av = &avv.x;
            const float* bv = &bvv.x;
#pragma unroll
            for (int i = 0; i < 4; ++i)
#pragma unroll
                for (int j = 0; j < 4; ++j)
                    acc[i][j] = fmaf(av[i], bv[j], acc[i][j]);
        }
    }

#pragma unroll
    for (int i = 0; i < 4; ++i) {
#pragma unroll
        for (int j = 0; j < 4; ++j) {
            const int c = tx * 4 + j;                       // within-64 true col
            float v = acc[i][j] + bias[n0 + c] + bias2[n0 + c];
            const int pos = n0 + 4 * (c & 15) + (c >> 4);   // permuted position
            C[(size_t)(m0 + ty * 4 + i) * N + pos] = v;
        }
    }
}

// ---------------------------------------------------------------------------
// Phase 3 GEMM: A (hs) is bf16 in PERMUTED position space. Instead of
// un-permuting A, gather B (Wo) K-dim through the same permutation — the dot
// product over positions equals the dot over true k.
// ---------------------------------------------------------------------------
__global__ __launch_bounds__(256) void gemm_bf16a_bt(
    const unsigned short* __restrict__ A, const float* __restrict__ B,
    const float* __restrict__ bias, float* __restrict__ C,
    int M, int N, int K)
{
    __shared__ __align__(16) float As[BKT][BM + 4];
    __shared__ __align__(16) float Bs[BKT][BN + 4];

    const int t  = threadIdx.x;
    const int m0 = blockIdx.x * BM;
    const int n0 = blockIdx.y * BN;
    const int r  = t >> 3;
    const int kq = (t & 7) * 4;
    const int tx = t & 15;
    const int ty = t >> 4;

    float acc[4][4] = {};

    for (int k0 = 0; k0 < K; k0 += BKT) {
        ushortv4 a0 = *(const ushortv4*)&A[(size_t)(m0 + r)      * K + k0 + kq];
        ushortv4 a1 = *(const ushortv4*)&A[(size_t)(m0 + r + 32) * K + k0 + kq];
        // gather Wo through the permutation (4 scalar loads per row)
        const int tk0 = true_k(k0 + kq + 0), tk1 = true_k(k0 + kq + 1);
        const int tk2 = true_k(k0 + kq + 2), tk3 = true_k(k0 + kq + 3);
        const float* br0 = B + (size_t)(n0 + r) * K;
        const float* br1 = B + (size_t)(n0 + r + 32) * K;
        float b00 = br0[tk0], b01 = br0[tk1], b02 = br0[tk2], b03 = br0[tk3];
        float b10 = br1[tk0], b11 = br1[tk1], b12 = br1[tk2], b13 = br1[tk3];

        __syncthreads();
        As[kq + 0][r] = bf16bits_to_f32(a0[0]); As[kq + 1][r] = bf16bits_to_f32(a0[1]);
        As[kq + 2][r] = bf16bits_to_f32(a0[2]); As[kq + 3][r] = bf16bits_to_f32(a0[3]);
        As[kq + 0][r + 32] = bf16bits_to_f32(a1[0]); As[kq + 1][r + 32] = bf16bits_to_f32(a1[1]);
        As[kq + 2][r + 32] = bf16bits_to_f32(a1[2]); As[kq + 3][r + 32] = bf16bits_to_f32(a1[3]);
        Bs[kq + 0][r] = b00; Bs[kq + 1][r] = b01; Bs[kq + 2][r] = b02; Bs[kq + 3][r] = b03;
        Bs[kq + 0][r + 32] = b10; Bs[kq + 1][r + 32] = b11; Bs[kq + 2][r + 32] = b12; Bs[kq + 3][r + 32] = b13;
        __syncthreads();

#pragma unroll
        for (int k = 0; k < BKT; ++k) {
            float4 avv = *(const float4*)&As[k][ty * 4];
            float4 bvv = *(const float4*)&Bs[k][tx * 4];
            const float* av = &avv.x;
            const float* bv = &bvv.x;
#pragma unroll
            for (int i = 0; i < 4; ++i)
#pragma unroll
                for (int j = 0; j < 4; ++j)
                    acc[i][j] = fmaf(av[i], bv[j], acc[i][j]);
        }
    }

#pragma unroll
    for (int i = 0; i < 4; ++i) {
        float4 o;
        o.x = acc[i][0] + bias[n0 + tx * 4 + 0];
        o.y = acc[i][1] + bias[n0 + tx * 4 + 1];
        o.z = acc[i][2] + bias[n0 + tx * 4 + 2];
        o.w = acc[i][3] + bias[n0 + tx * 4 + 3];
        *(float4*)&C[(size_t)(m0 + ty * 4 + i) * N + n0 + tx * 4] = o;
    }
}

// ---------------------------------------------------------------------------
// Recurrence v7: 4 blocks x 256 threads (4 waves, 1 wave/SIMD, 512-reg budget
// via waves_per_eu(1,1)). Wave owns 64 units (4 N-tiles) -> per-CU LDS A-read
// halves vs v6 (32 ds_read_b128 ~385cyc, was 64 ~770). Within-64 permuted
// layout: per row one dwordx4 x-load (C-fold), one ds_write_b64 h-write, one
// deferred dwordx2 hs store. bh folded into phase-1 bias.
// ---------------------------------------------------------------------------
#define G 16
#define HPAD 264    // ushorts per h row: 528B stride -> 2-way (free) banks

__global__ __launch_bounds__(256) __attribute__((amdgpu_waves_per_eu(1, 1)))
void rnn_recurrence_mfma(
    const float* __restrict__ xproj, const float* __restrict__ Wh,
    unsigned short* __restrict__ hs)
{
    __shared__ __align__(16) unsigned short hbl[2][G][HPAD];

    const int blk  = blockIdx.x;         // 0..3
    const int tid  = threadIdx.x;        // 0..255
    const int wave = tid >> 6;           // 0..3
    const int lane = tid & 63;
    const int l15  = lane & 15;
    const int lg   = lane >> 4;          // 0..3
    const int n0   = wave * 64;          // wave's 64-unit block
    const int row  = lg * 4;             // first of this lane's 4 batch rows

    // ---- one-time B-fragments: 4 N-tiles x 8 K-subtiles, position-space K
    // B[nt][kt] element b: col = n0+16*nt+l15 (true), k = true_k(kt*32+lg*8+b)
#define LB1(dst, b, pkv) { const int p64_ = (pkv) & 63; \
    const int tk_ = ((pkv) & ~63) + 16 * (p64_ & 3) + (p64_ >> 2); \
    dst[b] = (short)f2bf(wrow_[tk_]); }
#define LOADB(nt, kt, dst) { \
    const float* wrow_ = Wh + (size_t)(n0 + (nt) * 16 + l15) * HH; \
    const int pk_ = (kt) * 32 + lg * 8; \
    LB1(dst, 0, pk_ + 0) LB1(dst, 1, pk_ + 1) LB1(dst, 2, pk_ + 2) LB1(dst, 3, pk_ + 3) \
    LB1(dst, 4, pk_ + 4) LB1(dst, 5, pk_ + 5) LB1(dst, 6, pk_ + 6) LB1(dst, 7, pk_ + 7) }

    bf16x8 B00, B01, B02, B03, B04, B05, B06, B07;
    bf16x8 B10, B11, B12, B13, B14, B15, B16, B17;
    bf16x8 B20, B21, B22, B23, B24, B25, B26, B27;
    bf16x8 B30, B31, B32, B33, B34, B35, B36, B37;
    LOADB(0, 0, B00) LOADB(0, 1, B01) LOADB(0, 2, B02) LOADB(0, 3, B03)
    LOADB(0, 4, B04) LOADB(0, 5, B05) LOADB(0, 6, B06) LOADB(0, 7, B07)
    LOADB(1, 0, B10) LOADB(1, 1, B11) LOADB(1, 2, B12) LOADB(1, 3, B13)
    LOADB(1, 4, B14) LOADB(1, 5, B15) LOADB(1, 6, B16) LOADB(1, 7, B17)
    LOADB(2, 0, B20) LOADB(2, 1, B21) LOADB(2, 2, B22) LOADB(2, 3, B23)
    LOADB(2, 4, B24) LOADB(2, 5, B25) LOADB(2, 6, B26) LOADB(2, 7, B27)
    LOADB(3, 0, B30) LOADB(3, 1, B31) LOADB(3, 2, B32) LOADB(3, 3, B33)
    LOADB(3, 4, B34) LOADB(3, 5, B35) LOADB(3, 6, B36) LOADB(3, 7, B37)

    // per-row base pointers (batch gb+r), permuted column offset n0+4*l15
    const int gb = blk * G + row;
    const float* xq0 = xproj + (size_t)(gb + 0) * TT * HH + n0 + 4 * l15;
    const float* xq1 = xproj + (size_t)(gb + 1) * TT * HH + n0 + 4 * l15;
    const float* xq2 = xproj + (size_t)(gb + 2) * TT * HH + n0 + 4 * l15;
    const float* xq3 = xproj + (size_t)(gb + 3) * TT * HH + n0 + 4 * l15;
    unsigned short* hq0 = hs + (size_t)(gb + 0) * TT * HH + n0 + 4 * l15;
    unsigned short* hq1 = hs + (size_t)(gb + 1) * TT * HH + n0 + 4 * l15;
    unsigned short* hq2 = hs + (size_t)(gb + 2) * TT * HH + n0 + 4 * l15;
    unsigned short* hq3 = hs + (size_t)(gb + 3) * TT * HH + n0 + 4 * l15;

    // prologue: zero both h buffers; load x for t=0
    for (int i = tid; i < (int)(sizeof(hbl) / 4); i += 256)
        ((unsigned int*)hbl)[i] = 0u;
    float4 xv0 = *(const float4*)xq0;
    float4 xv1 = *(const float4*)xq1;
    float4 xv2 = *(const float4*)xq2;
    float4 xv3 = *(const float4*)xq3;
    __syncthreads();

    uint2 sv0 = {0, 0}, sv1 = {0, 0}, sv2 = {0, 0}, sv3 = {0, 0};

    for (int t = 0; t < TT; ++t) {
        const int p = t & 1;

        // A-fragments of current h (8 x ds_read_b128)
        const unsigned short* hrow = &hbl[p][l15][lg * 8];
        bf16x8 a0 = *(const bf16x8*)(hrow + 0 * 32);
        bf16x8 a1 = *(const bf16x8*)(hrow + 1 * 32);
        bf16x8 a2 = *(const bf16x8*)(hrow + 2 * 32);
        bf16x8 a3 = *(const bf16x8*)(hrow + 3 * 32);
        bf16x8 a4 = *(const bf16x8*)(hrow + 4 * 32);
        bf16x8 a5 = *(const bf16x8*)(hrow + 5 * 32);
        bf16x8 a6 = *(const bf16x8*)(hrow + 6 * 32);
        bf16x8 a7 = *(const bf16x8*)(hrow + 7 * 32);

        // deferred hs stores for t-1 (vmcnt drain overlaps this whole step)
        if (t) {
            *(uint2*)hq0 = sv0; hq0 += HH;
            *(uint2*)hq1 = sv1; hq1 += HH;
            *(uint2*)hq2 = sv2; hq2 += HH;
            *(uint2*)hq3 = sv3; hq3 += HH;
        }

        // 32 MFMA: 4 independent N-tile chains of 8
        f32x4v c0 = {0.f, 0.f, 0.f, 0.f}, c1 = {0.f, 0.f, 0.f, 0.f};
        f32x4v c2 = {0.f, 0.f, 0.f, 0.f}, c3 = {0.f, 0.f, 0.f, 0.f};
        c0 = __builtin_amdgcn_mfma_f32_16x16x32_bf16(a0, B00, c0, 0, 0, 0);
        c1 = __builtin_amdgcn_mfma_f32_16x16x32_bf16(a0, B10, c1, 0, 0, 0);
        c2 = __builtin_amdgcn_mfma_f32_16x16x32_bf16(a0, B20, c2, 0, 0, 0);
        c3 = __builtin_amdgcn_mfma_f32_16x16x32_bf16(a0, B30, c3, 0, 0, 0);
        c0 = __builtin_amdgcn_mfma_f32_16x16x32_bf16(a1, B01, c0, 0, 0, 0);
        c1 = __builtin_amdgcn_mfma_f32_16x16x32_bf16(a1, B11, c1, 0, 0, 0);
        c2 = __builtin_amdgcn_mfma_f32_16x16x32_bf16(a1, B21, c2, 0, 0, 0);
        c3 = __builtin_amdgcn_mfma_f32_16x16x32_bf16(a1, B31, c3, 0, 0, 0);
        c0 = __builtin_amdgcn_mfma_f32_16x16x32_bf16(a2, B02, c0, 0, 0, 0);
        c1 = __builtin_amdgcn_mfma_f32_16x16x32_bf16(a2, B12, c1, 0, 0, 0);
        c2 = __builtin_amdgcn_mfma_f32_16x16x32_bf16(a2, B22, c2, 0, 0, 0);
        c3 = __builtin_amdgcn_mfma_f32_16x16x32_bf16(a2, B32, c3, 0, 0, 0);
        c0 = __builtin_amdgcn_mfma_f32_16x16x32_bf16(a3, B03, c0, 0, 0, 0);
        c1 = __builtin_amdgcn_mfma_f32_16x16x32_bf16(a3, B13, c1, 0, 0, 0);
        c2 = __builtin_amdgcn_mfma_f32_16x16x32_bf16(a3, B23, c2, 0, 0, 0);
        c3 = __builtin_amdgcn_mfma_f32_16x16x32_bf16(a3, B33, c3, 0, 0, 0);
        c0 = __builtin_amdgcn_mfma_f32_16x16x32_bf16(a4, B04, c0, 0, 0, 0);
        c1 = __builtin_amdgcn_mfma_f32_16x16x32_bf16(a4, B14, c1, 0, 0, 0);
        c2 = __builtin_amdgcn_mfma_f32_16x16x32_bf16(a4, B24, c2, 0, 0, 0);
        c3 = __builtin_amdgcn_mfma_f32_16x16x32_bf16(a4, B34, c3, 0, 0, 0);
        c0 = __builtin_amdgcn_mfma_f32_16x16x32_bf16(a5, B05, c0, 0, 0, 0);
        c1 = __builtin_amdgcn_mfma_f32_16x16x32_bf16(a5, B15, c1, 0, 0, 0);
        c2 = __builtin_amdgcn_mfma_f32_16x16x32_bf16(a5, B25, c2, 0, 0, 0);
        c3 = __builtin_amdgcn_mfma_f32_16x16x32_bf16(a5, B35, c3, 0, 0, 0);
        c0 = __builtin_amdgcn_mfma_f32_16x16x32_bf16(a6, B06, c0, 0, 0, 0);
        c1 = __builtin_amdgcn_mfma_f32_16x16x32_bf16(a6, B16, c1, 0, 0, 0);
        c2 = __builtin_amdgcn_mfma_f32_16x16x32_bf16(a6, B26, c2, 0, 0, 0);
        c3 = __builtin_amdgcn_mfma_f32_16x16x32_bf16(a6, B36, c3, 0, 0, 0);
        c0 = __builtin_amdgcn_mfma_f32_16x16x32_bf16(a7, B07, c0, 0, 0, 0);
        c1 = __builtin_amdgcn_mfma_f32_16x16x32_bf16(a7, B17, c1, 0, 0, 0);
        c2 = __builtin_amdgcn_mfma_f32_16x16x32_bf16(a7, B27, c2, 0, 0, 0);
        c3 = __builtin_amdgcn_mfma_f32_16x16x32_bf16(a7, B37, c3, 0, 0, 0);

        // epilogue per row: add x (position-matched), tanh, pack, one b64 write
#define EPI(r, xv, sv) { \
        float h0 = tanh_fast(c0[r] + xv.x); \
        float h1 = tanh_fast(c1[r] + xv.y); \
        float h2 = tanh_fast(c2[r] + xv.z); \
        float h3 = tanh_fast(c3[r] + xv.w); \
        unsigned int pa_, pb_; \
        asm("v_cvt_pk_bf16_f32 %0, %1, %2" : "=v"(pa_) : "v"(h0), "v"(h1)); \
        asm("v_cvt_pk_bf16_f32 %0, %1, %2" : "=v"(pb_) : "v"(h2), "v"(h3)); \
        sv.x = pa_; sv.y = pb_; \
        *(uint2*)&hbl[p ^ 1][row + (r)][n0 + 4 * l15] = sv; }

        EPI(0, xv0, sv0)
        EPI(1, xv1, sv1)
        EPI(2, xv2, sv2)
        EPI(3, xv3, sv3)

        // prefetch x for t+1
        const size_t xoff = (size_t)((t + 1 < TT) ? (t + 1) : (TT - 1)) * HH;
        xv0 = *(const float4*)(xq0 + xoff);
        xv1 = *(const float4*)(xq1 + xoff);
        xv2 = *(const float4*)(xq2 + xoff);
        xv3 = *(const float4*)(xq3 + xoff);

        __syncthreads();
    }

    // final stores (t = TT-1)
    *(uint2*)hq0 = sv0;
    *(uint2*)hq1 = sv1;
    *(uint2*)hq2 = sv2;
    *(uint2*)hq3 = sv3;
}

// ---------------------------------------------------------------------------
extern "C" void kernel_launch(void* const* d_in, const int* in_sizes, int n_in,
                              void* d_out, int out_size, void* d_ws, size_t ws_size,
                              hipStream_t stream)
{
    const float* x  = (const float*)d_in[0];   // [B,T,I]
    const float* Wi = (const float*)d_in[1];   // [H,I]
    const float* bi = (const float*)d_in[2];   // [H]
    const float* Wh = (const float*)d_in[3];   // [H,H]
    const float* bh = (const float*)d_in[4];   // [H]
    const float* Wo = (const float*)d_in[5];   // [O,H]
    const float* bo = (const float*)d_in[6];   // [O]
    float* out = (float*)d_out;                // [B,T,O] fp32

    const int M = BB * TT;                     // 131072 flattened rows

    // workspace layout: xproj fp32 [M,H] (134MB, permuted) | hs bf16 [M,H] (67MB, permuted)
    float* xproj = (float*)d_ws;
    unsigned short* hs = (unsigned short*)((char*)d_ws + (size_t)M * HH * sizeof(float));

    // Phase 1: xproj = x*Wi^T + (bi+bh), permuted column layout
    gemm_f32_bt<<<dim3(M / BM, HH / BN), 256, 0, stream>>>(x, Wi, bi, bh, xproj, M, HH, II);

    // Phase 2: recurrence (4 CUs, MFMA, permuted position space)
    rnn_recurrence_mfma<<<dim3(4), 256, 0, stream>>>(xproj, Wh, hs);

    // Phase 3: out = hs*Wo^T + bo (Wo K-gathered through the permutation)
    gemm_bf16a_bt<<<dim3(M / BM, OO / BN), 256, 0, stream>>>(
        hs, Wo, bo, out, M, OO, HH);
}

// Round 8
// 1409.780 us; speedup vs baseline: 1.2910x; 1.2910x over previous
//
#include <hip/hip_runtime.h>
#include <hip/hip_bf16.h>

// Problem constants
#define BB 64
#define TT 2048
#define II 128
#define HH 256
#define OO 128

typedef float f32x4v __attribute__((ext_vector_type(4)));
typedef short bf16x8 __attribute__((ext_vector_type(8)));
typedef unsigned short ushortv4 __attribute__((ext_vector_type(4)));

__device__ __forceinline__ float bf16bits_to_f32(unsigned short u) {
    return __uint_as_float((unsigned)u << 16);
}
__device__ __forceinline__ unsigned short f2bf(float f) {
    union { __hip_bfloat16 h; unsigned short u; } cv;
    cv.h = __float2bfloat16(f);   // RNE
    return cv.u;
}
__device__ __forceinline__ float tanh_fast(float x) {
    // tanh(x) = 1 - 2/(e^{2x}+1);  e^{2x} = 2^{x*2*log2(e)}  (1 mul + 2 trans)
    float y = x * 2.88539008177793f;
    float e;
    asm("v_exp_f32 %0, %1" : "=v"(e) : "v"(y));
    return 1.0f - 2.0f * __builtin_amdgcn_rcpf(e + 1.0f);
}

// within-32 permutation: storage position p holds true column
//   T(p) = (p & ~31) + 16*(p&1) + ((p&31)>>1)
// inverse: pos(c) = (c & ~31) + 2*(c&15) + ((c&31)>>4)

// ---------------------------------------------------------------------------
// Phase 1 GEMM: xproj[m][pos] = (x*Wi^T)[m][T(pos)] + bi + bh  (permuted
// column layout so the recurrence's x loads are dwordx2; combined bias).
// ---------------------------------------------------------------------------
#define BM 64
#define BN 64
#define BKT 32

__global__ __launch_bounds__(256) void gemm_f32_bt(
    const float* __restrict__ A, const float* __restrict__ B,
    const float* __restrict__ bias, const float* __restrict__ bias2,
    float* __restrict__ C, int M, int N, int K)
{
    __shared__ __align__(16) float As[BKT][BM + 4];
    __shared__ __align__(16) float Bs[BKT][BN + 4];

    const int t  = threadIdx.x;
    const int m0 = blockIdx.x * BM;
    const int n0 = blockIdx.y * BN;
    const int r  = t >> 3;         // 0..31
    const int kq = (t & 7) * 4;    // 0,4,...,28
    const int tx = t & 15;
    const int ty = t >> 4;

    float acc[4][4] = {};

    for (int k0 = 0; k0 < K; k0 += BKT) {
        float4 a0 = *(const float4*)&A[(size_t)(m0 + r)      * K + k0 + kq];
        float4 a1 = *(const float4*)&A[(size_t)(m0 + r + 32) * K + k0 + kq];
        float4 b0 = *(const float4*)&B[(size_t)(n0 + r)      * K + k0 + kq];
        float4 b1 = *(const float4*)&B[(size_t)(n0 + r + 32) * K + k0 + kq];

        __syncthreads();
        As[kq + 0][r] = a0.x; As[kq + 1][r] = a0.y; As[kq + 2][r] = a0.z; As[kq + 3][r] = a0.w;
        As[kq + 0][r + 32] = a1.x; As[kq + 1][r + 32] = a1.y; As[kq + 2][r + 32] = a1.z; As[kq + 3][r + 32] = a1.w;
        Bs[kq + 0][r] = b0.x; Bs[kq + 1][r] = b0.y; Bs[kq + 2][r] = b0.z; Bs[kq + 3][r] = b0.w;
        Bs[kq + 0][r + 32] = b1.x; Bs[kq + 1][r + 32] = b1.y; Bs[kq + 2][r + 32] = b1.z; Bs[kq + 3][r + 32] = b1.w;
        __syncthreads();

#pragma unroll
        for (int k = 0; k < BKT; ++k) {
            float4 avv = *(const float4*)&As[k][ty * 4];
            float4 bvv = *(const float4*)&Bs[k][tx * 4];
            const float* av = &avv.x;
            const float* bv = &bvv.x;
#pragma unroll
            for (int i = 0; i < 4; ++i)
#pragma unroll
                for (int j = 0; j < 4; ++j)
                    acc[i][j] = fmaf(av[i], bv[j], acc[i][j]);
        }
    }

#pragma unroll
    for (int i = 0; i < 4; ++i) {
#pragma unroll
        for (int j = 0; j < 4; ++j) {
            const int c = n0 + tx * 4 + j;     // true column
            float v = acc[i][j] + bias[c] + bias2[c];
            const int pos = (c & ~31) + 2 * (c & 15) + ((c & 31) >> 4);
            C[(size_t)(m0 + ty * 4 + i) * N + pos] = v;
        }
    }
}

// ---------------------------------------------------------------------------
// Phase 3 GEMM (v6-verified): A (hs) bf16 with within-32 PERMUTED columns;
// the As staging un-permutes (rows {kh, kh+16, kh+1, kh+17} for kq block).
// ---------------------------------------------------------------------------
__global__ __launch_bounds__(256) void gemm_bf16a_bt(
    const unsigned short* __restrict__ A, const float* __restrict__ B,
    const float* __restrict__ bias, float* __restrict__ C,
    int M, int N, int K)
{
    __shared__ __align__(16) float As[BKT][BM + 4];
    __shared__ __align__(16) float Bs[BKT][BN + 4];

    const int t  = threadIdx.x;
    const int m0 = blockIdx.x * BM;
    const int n0 = blockIdx.y * BN;
    const int r  = t >> 3;
    const int kq = (t & 7) * 4;
    const int kh = kq >> 1;        // un-permute
    const int tx = t & 15;
    const int ty = t >> 4;

    float acc[4][4] = {};

    for (int k0 = 0; k0 < K; k0 += BKT) {
        ushortv4 a0 = *(const ushortv4*)&A[(size_t)(m0 + r)      * K + k0 + kq];
        ushortv4 a1 = *(const ushortv4*)&A[(size_t)(m0 + r + 32) * K + k0 + kq];
        float4  b0 = *(const float4*)&B[(size_t)(n0 + r)      * K + k0 + kq];
        float4  b1 = *(const float4*)&B[(size_t)(n0 + r + 32) * K + k0 + kq];

        __syncthreads();
        As[kh + 0][r]  = bf16bits_to_f32(a0[0]); As[kh + 16][r] = bf16bits_to_f32(a0[1]);
        As[kh + 1][r]  = bf16bits_to_f32(a0[2]); As[kh + 17][r] = bf16bits_to_f32(a0[3]);
        As[kh + 0][r + 32]  = bf16bits_to_f32(a1[0]); As[kh + 16][r + 32] = bf16bits_to_f32(a1[1]);
        As[kh + 1][r + 32]  = bf16bits_to_f32(a1[2]); As[kh + 17][r + 32] = bf16bits_to_f32(a1[3]);
        Bs[kq + 0][r] = b0.x; Bs[kq + 1][r] = b0.y; Bs[kq + 2][r] = b0.z; Bs[kq + 3][r] = b0.w;
        Bs[kq + 0][r + 32] = b1.x; Bs[kq + 1][r + 32] = b1.y; Bs[kq + 2][r + 32] = b1.z; Bs[kq + 3][r + 32] = b1.w;
        __syncthreads();

#pragma unroll
        for (int k = 0; k < BKT; ++k) {
            float4 avv = *(const float4*)&As[k][ty * 4];
            float4 bvv = *(const float4*)&Bs[k][tx * 4];
            const float* av = &avv.x;
            const float* bv = &bvv.x;
#pragma unroll
            for (int i = 0; i < 4; ++i)
#pragma unroll
                for (int j = 0; j < 4; ++j)
                    acc[i][j] = fmaf(av[i], bv[j], acc[i][j]);
        }
    }

#pragma unroll
    for (int i = 0; i < 4; ++i) {
        float4 o;
        o.x = acc[i][0] + bias[n0 + tx * 4 + 0];
        o.y = acc[i][1] + bias[n0 + tx * 4 + 1];
        o.z = acc[i][2] + bias[n0 + tx * 4 + 2];
        o.w = acc[i][3] + bias[n0 + tx * 4 + 3];
        *(float4*)&C[(size_t)(m0 + ty * 4 + i) * N + n0 + tx * 4] = o;
    }
}

// ---------------------------------------------------------------------------
// Recurrence v8 = v6 (8 waves, 2/SIMD — proven best latency regime) with the
// VALU fat trimmed:
//   - bh folded into phase-1 bias (no C-init splats)
//   - 2 merged chains of 8 MFMA (C-in = x loads directly; no zero-chains, no
//     final adds)
//   - x loaded as 4 dwordx2 from within-32-PERMUTED xproj (was 8 scalars)
//   - pointer-bump addressing; unconditional in-bounds prefetch
//   - deferred hs stores (v6), cvt_pk + b32 LDS writes (v6)
// ---------------------------------------------------------------------------
#define G 16
#define HPAD 264    // ushorts per h row (528B): write banks 2-way (free)

__global__ __launch_bounds__(512) __attribute__((amdgpu_waves_per_eu(2, 2)))
void rnn_recurrence_mfma(
    const float* __restrict__ xproj, const float* __restrict__ Wh,
    unsigned short* __restrict__ hs)
{
    __shared__ __align__(16) unsigned short hbl[2][G][HPAD];

    const int blk  = blockIdx.x;         // 0..3
    const int tid  = threadIdx.x;        // 0..511
    const int wave = tid >> 6;           // 0..7
    const int lane = tid & 63;
    const int l15  = lane & 15;
    const int lg   = lane >> 4;          // 0..3
    const int n0   = wave * 32;          // wave's 32-unit block

    // ---- one-time B-frags (v6-verified within-32 K-gather):
    // slot b of subtile kt: true k = kt*32 + lg*4 + (b>>1) + 16*(b&1)
#define LOADB(nt, kt, dst) { \
        const float* wp = Wh + (size_t)(n0 + (nt)*16 + l15) * HH + (kt)*32 + lg*4; \
        dst[0] = (short)f2bf(wp[0]);  dst[1] = (short)f2bf(wp[16]); \
        dst[2] = (short)f2bf(wp[1]);  dst[3] = (short)f2bf(wp[17]); \
        dst[4] = (short)f2bf(wp[2]);  dst[5] = (short)f2bf(wp[18]); \
        dst[6] = (short)f2bf(wp[3]);  dst[7] = (short)f2bf(wp[19]); }

    bf16x8 B00, B01, B02, B03, B04, B05, B06, B07;
    bf16x8 B10, B11, B12, B13, B14, B15, B16, B17;
    LOADB(0, 0, B00) LOADB(0, 1, B01) LOADB(0, 2, B02) LOADB(0, 3, B03)
    LOADB(0, 4, B04) LOADB(0, 5, B05) LOADB(0, 6, B06) LOADB(0, 7, B07)
    LOADB(1, 0, B10) LOADB(1, 1, B11) LOADB(1, 2, B12) LOADB(1, 3, B13)
    LOADB(1, 4, B14) LOADB(1, 5, B15) LOADB(1, 6, B16) LOADB(1, 7, B17)

    // per-thread 4 batch rows (m = lg*4 + r), permuted col offset n0 + 2*l15
    const int mb = blk * G + lg * 4;
    const float* xq0 = xproj + (size_t)(mb + 0) * TT * HH + n0 + 2 * l15;
    const float* xq1 = xproj + (size_t)(mb + 1) * TT * HH + n0 + 2 * l15;
    const float* xq2 = xproj + (size_t)(mb + 2) * TT * HH + n0 + 2 * l15;
    const float* xq3 = xproj + (size_t)(mb + 3) * TT * HH + n0 + 2 * l15;
    unsigned short* hq0 = hs + (size_t)(mb + 0) * TT * HH + n0 + 2 * l15;
    unsigned short* hq1 = hs + (size_t)(mb + 1) * TT * HH + n0 + 2 * l15;
    unsigned short* hq2 = hs + (size_t)(mb + 2) * TT * HH + n0 + 2 * l15;
    unsigned short* hq3 = hs + (size_t)(mb + 3) * TT * HH + n0 + 2 * l15;

    // prologue: zero h buffer 0; load x for t=0
    for (int i = tid; i < G * HPAD / 2; i += 512)
        ((unsigned int*)hbl[0])[i] = 0u;
    float2 xv0 = *(const float2*)xq0;
    float2 xv1 = *(const float2*)xq1;
    float2 xv2 = *(const float2*)xq2;
    float2 xv3 = *(const float2*)xq3;
    __syncthreads();

    unsigned int sv0 = 0, sv1 = 0, sv2 = 0, sv3 = 0;

    for (int t = 0; t < TT; ++t) {
        const int p = t & 1;

        // A-fragments of current h (8 x ds_read_b128)
        const unsigned short* hrow = &hbl[p][l15][lg * 8];
        bf16x8 a0 = *(const bf16x8*)(hrow + 0 * 32);
        bf16x8 a1 = *(const bf16x8*)(hrow + 1 * 32);
        bf16x8 a2 = *(const bf16x8*)(hrow + 2 * 32);
        bf16x8 a3 = *(const bf16x8*)(hrow + 3 * 32);
        bf16x8 a4 = *(const bf16x8*)(hrow + 4 * 32);
        bf16x8 a5 = *(const bf16x8*)(hrow + 5 * 32);
        bf16x8 a6 = *(const bf16x8*)(hrow + 6 * 32);
        bf16x8 a7 = *(const bf16x8*)(hrow + 7 * 32);

        // deferred hs stores for t-1 (drain overlaps this whole step)
        if (t) {
            *(unsigned int*)hq0 = sv0; hq0 += HH;
            *(unsigned int*)hq1 = sv1; hq1 += HH;
            *(unsigned int*)hq2 = sv2; hq2 += HH;
            *(unsigned int*)hq3 = sv3; hq3 += HH;
        }

        // 16 MFMA: 2 chains of 8, C-in = x (bias pre-folded in phase 1)
        f32x4v c0 = {xv0.x, xv1.x, xv2.x, xv3.x};
        f32x4v c1 = {xv0.y, xv1.y, xv2.y, xv3.y};
        c0 = __builtin_amdgcn_mfma_f32_16x16x32_bf16(a0, B00, c0, 0, 0, 0);
        c1 = __builtin_amdgcn_mfma_f32_16x16x32_bf16(a0, B10, c1, 0, 0, 0);
        c0 = __builtin_amdgcn_mfma_f32_16x16x32_bf16(a1, B01, c0, 0, 0, 0);
        c1 = __builtin_amdgcn_mfma_f32_16x16x32_bf16(a1, B11, c1, 0, 0, 0);
        c0 = __builtin_amdgcn_mfma_f32_16x16x32_bf16(a2, B02, c0, 0, 0, 0);
        c1 = __builtin_amdgcn_mfma_f32_16x16x32_bf16(a2, B12, c1, 0, 0, 0);
        c0 = __builtin_amdgcn_mfma_f32_16x16x32_bf16(a3, B03, c0, 0, 0, 0);
        c1 = __builtin_amdgcn_mfma_f32_16x16x32_bf16(a3, B13, c1, 0, 0, 0);
        c0 = __builtin_amdgcn_mfma_f32_16x16x32_bf16(a4, B04, c0, 0, 0, 0);
        c1 = __builtin_amdgcn_mfma_f32_16x16x32_bf16(a4, B14, c1, 0, 0, 0);
        c0 = __builtin_amdgcn_mfma_f32_16x16x32_bf16(a5, B05, c0, 0, 0, 0);
        c1 = __builtin_amdgcn_mfma_f32_16x16x32_bf16(a5, B15, c1, 0, 0, 0);
        c0 = __builtin_amdgcn_mfma_f32_16x16x32_bf16(a6, B06, c0, 0, 0, 0);
        c1 = __builtin_amdgcn_mfma_f32_16x16x32_bf16(a6, B16, c1, 0, 0, 0);
        c0 = __builtin_amdgcn_mfma_f32_16x16x32_bf16(a7, B07, c0, 0, 0, 0);
        c1 = __builtin_amdgcn_mfma_f32_16x16x32_bf16(a7, B17, c1, 0, 0, 0);

        // epilogue: tanh both chain outputs, pack, one b32 LDS write per row
#define EPI(r, sv) { \
        float h0 = tanh_fast(c0[r]); \
        float h1 = tanh_fast(c1[r]); \
        asm("v_cvt_pk_bf16_f32 %0, %1, %2" : "=v"(sv) : "v"(h0), "v"(h1)); \
        *(unsigned int*)&hbl[p ^ 1][lg * 4 + (r)][n0 + 2 * l15] = sv; }

        EPI(0, sv0)
        EPI(1, sv1)
        EPI(2, sv2)
        EPI(3, sv3)

        // prefetch x for t+1 (pointer bump; last-step read is in-bounds junk)
        xq0 += HH; xq1 += HH; xq2 += HH; xq3 += HH;
        xv0 = *(const float2*)xq0;
        xv1 = *(const float2*)xq1;
        xv2 = *(const float2*)xq2;
        xv3 = *(const float2*)xq3;

        __syncthreads();
    }

    // final stores (t = TT-1)
    *(unsigned int*)hq0 = sv0;
    *(unsigned int*)hq1 = sv1;
    *(unsigned int*)hq2 = sv2;
    *(unsigned int*)hq3 = sv3;
}

// ---------------------------------------------------------------------------
extern "C" void kernel_launch(void* const* d_in, const int* in_sizes, int n_in,
                              void* d_out, int out_size, void* d_ws, size_t ws_size,
                              hipStream_t stream)
{
    const float* x  = (const float*)d_in[0];   // [B,T,I]
    const float* Wi = (const float*)d_in[1];   // [H,I]
    const float* bi = (const float*)d_in[2];   // [H]
    const float* Wh = (const float*)d_in[3];   // [H,H]
    const float* bh = (const float*)d_in[4];   // [H]
    const float* Wo = (const float*)d_in[5];   // [O,H]
    const float* bo = (const float*)d_in[6];   // [O]
    float* out = (float*)d_out;                // [B,T,O] fp32

    const int M = BB * TT;                     // 131072 flattened rows

    // workspace: xproj fp32 [M,H] (134MB, permuted) | hs bf16 [M,H] (67MB, permuted)
    float* xproj = (float*)d_ws;
    unsigned short* hs = (unsigned short*)((char*)d_ws + (size_t)M * HH * sizeof(float));

    // Phase 1: xproj = x*Wi^T + (bi+bh), within-32 permuted columns
    gemm_f32_bt<<<dim3(M / BM, HH / BN), 256, 0, stream>>>(x, Wi, bi, bh, xproj, M, HH, II);

    // Phase 2: recurrence (4 CUs, 8 waves each, MFMA)
    rnn_recurrence_mfma<<<dim3(4), 512, 0, stream>>>(xproj, Wh, hs);

    // Phase 3: out = hs*Wo^T + bo (As staging un-permutes)
    gemm_bf16a_bt<<<dim3(M / BM, OO / BN), 256, 0, stream>>>(
        hs, Wo, bo, out, M, OO, HH);
}